// Round 1
// 63.531 us; speedup vs baseline: 1.1208x; 1.1208x over previous
//
#include <hip/hip_runtime.h>

#define B_SZ 256
#define D_SZ 256
#define N_TOT 512   // 2*B
#define NBLK 64     // blocks in fused kernel
#define NTHR 1024   // 16 waves/block -> 4 waves/SIMD (vs 1 before)

// ws layout (doubles): ws[0..63] = per-block signed loss partials

// ---------------------------------------------------------------------------
// Fused kernel: 64 blocks x 1024 threads.
// Phase A (redundant per block, 4x less traffic than 256-block version):
//   1024 threads = 4 row-groups x 256 cols. Group g reads 128 of the 512
//   global rows (g<2 -> src half, else tgt half), f32 split-chain partials,
//   LDS combine in f64, then weighted reduce ->
//   sum(l2_cum) = sum_d (D-d) * (2*n*S2[d] - 2*S1[d]^2) -> bandwidth.
// Phase B: wave w (0..15) handles pair wid = blockIdx*16 + w
//   (p = wid&255, type = wid>>8). Lane l covers dims [4l,4l+4): float4
//   loads, wave inclusive scan for the feature-axis cumsum, 5-bandwidth
//   Gaussian sum, signed double reduce. Block partial -> ws[blockIdx].
// ---------------------------------------------------------------------------
__global__ __launch_bounds__(NTHR) void fused_kernel(const float* __restrict__ src,
                                                     const float* __restrict__ tgt,
                                                     double* __restrict__ partial) {
    const int tx   = threadIdx.x;
    const int lane = tx & 63;
    const int wave = tx >> 6;          // 0..15

    // ---- Phase A: group g owns 128 of the 512 rows, column = tx&255 ----
    const int col = tx & 255;
    const int grp = tx >> 8;           // 0..3
    const float* base = (grp < 2) ? src : tgt;
    const float* ptr  = base + ((grp & 1) * 128) * D_SZ + col;

    // f32 partials over 128 values, 2 independent chains each (error on the
    // final bandwidth ~1e-8 relative; cross-group combine stays f64)
    float s1e = 0.f, s1o = 0.f, s2e = 0.f, s2o = 0.f;
    #pragma unroll 8
    for (int r = 0; r < 128; r += 2) {
        float a = ptr[r * D_SZ];
        float b = ptr[(r + 1) * D_SZ];
        s1e += a; s2e = fmaf(a, a, s2e);
        s1o += b; s2o = fmaf(b, b, s2o);
    }

    __shared__ float sh1[4][D_SZ];
    __shared__ float sh2[4][D_SZ];
    sh1[grp][col] = s1e + s1o;
    sh2[grp][col] = s2e + s2o;
    __syncthreads();

    __shared__ double shred[4];
    __shared__ double sh_bw;
    if (tx < 256) {                    // waves 0..3 do the column combine
        double S1 = (double)sh1[0][col] + (double)sh1[1][col]
                  + (double)sh1[2][col] + (double)sh1[3][col];
        double S2 = (double)sh2[0][col] + (double)sh2[1][col]
                  + (double)sh2[2][col] + (double)sh2[3][col];
        double pairsum = 2.0 * (double)N_TOT * S2 - 2.0 * S1 * S1;
        double local   = (double)(D_SZ - col) * pairsum;
        #pragma unroll
        for (int off = 32; off > 0; off >>= 1)
            local += __shfl_down(local, off, 64);
        if (lane == 0) shred[wave] = local;
    }
    __syncthreads();
    if (tx == 0) {
        double total = shred[0] + shred[1] + shred[2] + shred[3];
        // bandwidth = total/(n^2-n) / (kernel_mul^(num/2)) = total/(n^2-n)/4
        sh_bw = total / ((double)N_TOT * (double)(N_TOT - 1)) * 0.25;
    }
    __syncthreads();
    const float bw = (float)sh_bw;

    // ---- Phase B: wave -> pair (identical per-wave math to prior version) ----
    const int wid = blockIdx.x * 16 + wave;   // 0..1023
    const int p   = wid & 255;
    const int t   = wid >> 8;
    const int q   = (p + 1) & 255;

    const float* rowA;
    const float* rowB;
    double sign;
    if (t == 0)      { rowA = src + p * D_SZ; rowB = src + q * D_SZ; sign =  1.0; }
    else if (t == 1) { rowA = tgt + p * D_SZ; rowB = tgt + q * D_SZ; sign =  1.0; }
    else if (t == 2) { rowA = src + p * D_SZ; rowB = tgt + q * D_SZ; sign = -1.0; }
    else             { rowA = src + q * D_SZ; rowB = tgt + p * D_SZ; sign = -1.0; }

    float4 a4 = ((const float4*)rowA)[lane];
    float4 b4 = ((const float4*)rowB)[lane];
    float d0 = a4.x - b4.x, d1 = a4.y - b4.y, d2 = a4.z - b4.z, d3 = a4.w - b4.w;
    float c0 = d0 * d0;
    float c1 = c0 + d1 * d1;
    float c2 = c1 + d2 * d2;
    float c3 = c2 + d3 * d3;

    // inclusive wave scan of per-lane totals
    float s = c3;
    #pragma unroll
    for (int off = 1; off < 64; off <<= 1) {
        float v = __shfl_up(s, off, 64);
        if (lane >= off) s += v;
    }
    float prefix = __shfl_up(s, 1, 64);
    if (lane == 0) prefix = 0.f;

    float cum0 = prefix + c0;
    float cum1 = prefix + c1;
    float cum2 = prefix + c2;
    float cum3 = prefix + c3;

    float acc = 0.f;
    float inv = 1.0f / bw;
    #pragma unroll
    for (int k = 0; k < 5; ++k) {
        acc += expf(-cum0 * inv) + expf(-cum1 * inv) + expf(-cum2 * inv) + expf(-cum3 * inv);
        inv *= 0.5f;
    }

    double lacc = (double)acc * sign;
    #pragma unroll
    for (int off = 32; off > 0; off >>= 1)
        lacc += __shfl_down(lacc, off, 64);

    __shared__ double blk[16];
    if (lane == 0) blk[wave] = lacc;
    __syncthreads();
    if (tx == 0) {
        double sum = 0.0;
        #pragma unroll
        for (int w = 0; w < 16; ++w) sum += blk[w];
        partial[blockIdx.x] = sum;
    }
}

// ---------------------------------------------------------------------------
// Final: one wave reduces 64 block partials, out = sum / (B*D)
// ---------------------------------------------------------------------------
__global__ __launch_bounds__(64) void final_kernel(const double* __restrict__ partial,
                                                   float* __restrict__ out) {
    const int tx = threadIdx.x;
    double v = partial[tx];
    #pragma unroll
    for (int off = 32; off > 0; off >>= 1)
        v += __shfl_down(v, off, 64);
    if (tx == 0)
        out[0] = (float)(v * (1.0 / ((double)B_SZ * (double)D_SZ)));
}

extern "C" void kernel_launch(void* const* d_in, const int* in_sizes, int n_in,
                              void* d_out, int out_size, void* d_ws, size_t ws_size,
                              hipStream_t stream) {
    const float* src = (const float*)d_in[0];
    const float* tgt = (const float*)d_in[1];
    float* out = (float*)d_out;
    double* ws = (double*)d_ws;

    fused_kernel<<<NBLK, NTHR, 0, stream>>>(src, tgt, ws);
    final_kernel<<<1, 64, 0, stream>>>(ws, out);
}

// Round 2
// 62.211 us; speedup vs baseline: 1.1446x; 1.0212x over previous
//
#include <hip/hip_runtime.h>

#define B_SZ 256
#define D_SZ 256
#define N_TOT 512   // 2*B

// ---------------- workspace layout (bytes) ----------------
// [0      , 16384)  : float S1part[16][256]
// [16384  , 32768)  : float S2part[16][256]
// [32768  , 32776)  : double acc   (signed loss accumulator)
// [32776  , 32780)  : unsigned cnt (blocks-done counter)
#define WS_S2_OFF   4096      // in floats
#define WS_ACC_OFF  32768     // in bytes
#define WS_CNT_OFF  32776     // in bytes

#define K1_BLK 16
#define K1_THR 1024
#define K2_BLK 128
#define K2_THR 512

// ---------------------------------------------------------------------------
// K1: non-redundant column partial sums + ws accumulator init.
// 16 blocks x 1024 threads. Block b owns rows [32b, 32b+32) of the 512
// concatenated rows (blocks 0-7 -> src, 8-15 -> tgt; never straddles).
// 1024 thr = 4 row-groups x 256 cols; each thread reads 8 strided values.
// LDS-combine the 4 groups -> S1part[b][col], S2part[b][col] (f32 stores).
// Block 0 thread 0 zeroes the acc/cnt slots (poisoned every iteration).
// ---------------------------------------------------------------------------
__global__ __launch_bounds__(K1_THR) void prep_kernel(const float* __restrict__ src,
                                                      const float* __restrict__ tgt,
                                                      void* __restrict__ ws) {
    const int tx  = threadIdx.x;
    const int col = tx & 255;
    const int grp = tx >> 8;                    // 0..3
    const int row0 = blockIdx.x * 32 + grp * 8; // 0..504

    const float* ptr = (row0 < B_SZ ? src + row0 * D_SZ
                                    : tgt + (row0 - B_SZ) * D_SZ) + col;
    float s1 = 0.f, s2 = 0.f;
    #pragma unroll
    for (int i = 0; i < 8; ++i) {
        float a = ptr[i * D_SZ];
        s1 += a;
        s2 = fmaf(a, a, s2);
    }

    __shared__ float sh1[4][D_SZ];
    __shared__ float sh2[4][D_SZ];
    sh1[grp][col] = s1;
    sh2[grp][col] = s2;
    __syncthreads();

    float* wsf = (float*)ws;
    if (tx < 256) {
        wsf[blockIdx.x * 256 + tx] =
            sh1[0][tx] + sh1[1][tx] + sh1[2][tx] + sh1[3][tx];
        wsf[WS_S2_OFF + blockIdx.x * 256 + tx] =
            sh2[0][tx] + sh2[1][tx] + sh2[2][tx] + sh2[3][tx];
    }
    if (blockIdx.x == 0 && tx == 0) {
        *(double*)((char*)ws + WS_ACC_OFF)   = 0.0;
        *(unsigned*)((char*)ws + WS_CNT_OFF) = 0u;
    }
}

// ---------------------------------------------------------------------------
// K2: 128 blocks x 512 threads (8 waves). Wave w -> pair wid = blockIdx*8+w
// (1024 pairs exactly: p = wid&255, type = wid>>8).
//   1. Phase-B prework (bw-independent): float4 row loads, diffs, wave
//      inclusive scan for the feature-axis cumsum.
//   2. Redundant-but-cheap bw combine: tx<256 sums the 16 f32 partials per
//      column in f64, weighted reduce -> bandwidth (identical formula).
//   3. 5-bandwidth Gaussian sum, signed f64 wave/block reduce.
//   4. Block partial -> f64 atomicAdd(acc); last block (counter) writes out.
// ---------------------------------------------------------------------------
__global__ __launch_bounds__(K2_THR) void main_kernel(const float* __restrict__ src,
                                                      const float* __restrict__ tgt,
                                                      void* __restrict__ ws,
                                                      float* __restrict__ out) {
    const int tx   = threadIdx.x;
    const int lane = tx & 63;
    const int wave = tx >> 6;                   // 0..7

    // ---- 1. Phase-B prework ----
    const int wid = blockIdx.x * 8 + wave;      // 0..1023
    const int p   = wid & 255;
    const int t   = wid >> 8;
    const int q   = (p + 1) & 255;

    const float* rowA;
    const float* rowB;
    double sign;
    if (t == 0)      { rowA = src + p * D_SZ; rowB = src + q * D_SZ; sign =  1.0; }
    else if (t == 1) { rowA = tgt + p * D_SZ; rowB = tgt + q * D_SZ; sign =  1.0; }
    else if (t == 2) { rowA = src + p * D_SZ; rowB = tgt + q * D_SZ; sign = -1.0; }
    else             { rowA = src + q * D_SZ; rowB = tgt + p * D_SZ; sign = -1.0; }

    float4 a4 = ((const float4*)rowA)[lane];
    float4 b4 = ((const float4*)rowB)[lane];
    float d0 = a4.x - b4.x, d1 = a4.y - b4.y, d2 = a4.z - b4.z, d3 = a4.w - b4.w;
    float c0 = d0 * d0;
    float c1 = c0 + d1 * d1;
    float c2 = c1 + d2 * d2;
    float c3 = c2 + d3 * d3;

    float s = c3;
    #pragma unroll
    for (int off = 1; off < 64; off <<= 1) {
        float v = __shfl_up(s, off, 64);
        if (lane >= off) s += v;
    }
    float prefix = __shfl_up(s, 1, 64);
    if (lane == 0) prefix = 0.f;

    float cum0 = prefix + c0;
    float cum1 = prefix + c1;
    float cum2 = prefix + c2;
    float cum3 = prefix + c3;

    // ---- 2. bandwidth combine (waves 0..3) ----
    __shared__ double shred[4];
    __shared__ double sh_bw;
    if (tx < 256) {
        const float* wsf = (const float*)ws;
        double S1 = 0.0, S2 = 0.0;
        #pragma unroll
        for (int b = 0; b < 16; ++b) {
            S1 += (double)wsf[b * 256 + tx];
            S2 += (double)wsf[WS_S2_OFF + b * 256 + tx];
        }
        double pairsum = 2.0 * (double)N_TOT * S2 - 2.0 * S1 * S1;
        double local   = (double)(D_SZ - tx) * pairsum;
        #pragma unroll
        for (int off = 32; off > 0; off >>= 1)
            local += __shfl_down(local, off, 64);
        if (lane == 0) shred[wave] = local;
    }
    __syncthreads();
    if (tx == 0) {
        double total = shred[0] + shred[1] + shred[2] + shred[3];
        // bandwidth = total/(n^2-n) / (kernel_mul^(num/2)) = total/(n^2-n)/4
        sh_bw = total / ((double)N_TOT * (double)(N_TOT - 1)) * 0.25;
    }
    __syncthreads();
    const float bw = (float)sh_bw;

    // ---- 3. multi-kernel Gaussian sum ----
    float acc = 0.f;
    float inv = 1.0f / bw;
    #pragma unroll
    for (int k = 0; k < 5; ++k) {
        acc += expf(-cum0 * inv) + expf(-cum1 * inv) + expf(-cum2 * inv) + expf(-cum3 * inv);
        inv *= 0.5f;
    }

    double lacc = (double)acc * sign;
    #pragma unroll
    for (int off = 32; off > 0; off >>= 1)
        lacc += __shfl_down(lacc, off, 64);

    __shared__ double blk[8];
    if (lane == 0) blk[wave] = lacc;
    __syncthreads();

    // ---- 4. cross-block combine via atomics (slots zeroed by K1) ----
    if (tx == 0) {
        double bsum = 0.0;
        #pragma unroll
        for (int w = 0; w < 8; ++w) bsum += blk[w];

        double*   accp = (double*)((char*)ws + WS_ACC_OFF);
        unsigned* cntp = (unsigned*)((char*)ws + WS_CNT_OFF);
        atomicAdd(accp, bsum);
        __threadfence();
        unsigned old = atomicAdd(cntp, 1u);
        if (old == K2_BLK - 1) {
            double total = __hip_atomic_load(accp, __ATOMIC_ACQUIRE,
                                             __HIP_MEMORY_SCOPE_AGENT);
            out[0] = (float)(total * (1.0 / ((double)B_SZ * (double)D_SZ)));
        }
    }
}

extern "C" void kernel_launch(void* const* d_in, const int* in_sizes, int n_in,
                              void* d_out, int out_size, void* d_ws, size_t ws_size,
                              hipStream_t stream) {
    const float* src = (const float*)d_in[0];
    const float* tgt = (const float*)d_in[1];
    float* out = (float*)d_out;

    prep_kernel<<<K1_BLK, K1_THR, 0, stream>>>(src, tgt, d_ws);
    main_kernel<<<K2_BLK, K2_THR, 0, stream>>>(src, tgt, d_ws, out);
}